// Round 1
// baseline (467.279 us; speedup 1.0000x reference)
//
#include <hip/hip_runtime.h>
#include <hip/hip_bf16.h>

#define BATCH 8192
#define DIM 64
#define INV_TEMP 14.2857142857142857f  // 1/0.07
#define EPS_NORM 1e-8f

// ---------------------------------------------------------------------------
// Kernel 1: per-row inverse norms (one wave per row), zero numer/denom accums
// ---------------------------------------------------------------------------
__global__ __launch_bounds__(256) void norm_kernel(
    const float* __restrict__ A, const float* __restrict__ Bm,
    float* __restrict__ inv_na, float* __restrict__ inv_nb,
    float* __restrict__ numer, float* __restrict__ denom) {
  int gid  = blockIdx.x * 256 + threadIdx.x;
  int row  = gid >> 6;
  int lane = gid & 63;
  float a = A[row * DIM + lane];
  float b = Bm[row * DIM + lane];
  float sa = a * a, sb = b * b;
#pragma unroll
  for (int m = 32; m; m >>= 1) {
    sa += __shfl_xor(sa, m);
    sb += __shfl_xor(sb, m);
  }
  if (lane == 0) {
    inv_na[row] = 1.0f / fmaxf(sqrtf(sa), EPS_NORM);
    inv_nb[row] = 1.0f / fmaxf(sqrtf(sb), EPS_NORM);
    numer[row] = 0.0f;  // ws is poisoned 0xAA every launch — must re-zero
    denom[row] = 0.0f;
  }
}

// ---------------------------------------------------------------------------
// Kernel 2: 64x64 cos tile + fused exp / label-masked row sums
//   block = 256 threads = 16x16; each thread computes a 4x4 micro-tile
//   cols strided by 16 so epilogue dword stores are dense 64B segments
//   (d_out+1 is only 4B aligned -> no float4 stores on output)
// ---------------------------------------------------------------------------
__global__ __launch_bounds__(256) void cos_tile_kernel(
    const float* __restrict__ A, const float* __restrict__ Bm,
    const int* __restrict__ labels,
    const float* __restrict__ inv_na, const float* __restrict__ inv_nb,
    float* __restrict__ numer, float* __restrict__ denom,
    float* __restrict__ cos_out) {
  // +4 pad: keeps 16B alignment for ds_read_b128 (stride 68*4=272 B ≡ 0 mod 16)
  __shared__ float As[64][68];
  __shared__ float Bs[64][68];
  __shared__ int   laS[64], lbS[64];
  __shared__ float inaS[64], inbS[64];

  const int tid = threadIdx.x;
  const int bx = blockIdx.x;  // col tile
  const int by = blockIdx.y;  // row tile

  // ---- stage A/B tiles (4096 floats each; 4x float4 per thread, coalesced)
  {
    const float* Ag = A + (size_t)by * 64 * DIM;
    const float* Bg = Bm + (size_t)bx * 64 * DIM;
#pragma unroll
    for (int it = 0; it < 4; ++it) {
      int idx = it * 1024 + tid * 4;
      int r = idx >> 6, c = idx & 63;
      float4 va = *(const float4*)(Ag + idx);
      float4 vb = *(const float4*)(Bg + idx);
      *(float4*)&As[r][c] = va;
      *(float4*)&Bs[r][c] = vb;
    }
    if (tid < 64) {
      laS[tid]  = labels[by * 64 + tid];
      inaS[tid] = inv_na[by * 64 + tid];
    } else if (tid < 128) {
      int t = tid - 64;
      lbS[t]  = labels[bx * 64 + t];
      inbS[t] = inv_nb[bx * 64 + t];
    }
  }
  __syncthreads();

  const int tx = tid & 15;   // col group (16 threads wide)
  const int ty = tid >> 4;   // row group

  float acc[4][4] = {};
#pragma unroll 4
  for (int kk = 0; kk < 64; kk += 4) {
    float4 a[4], b[4];
#pragma unroll
    for (int i = 0; i < 4; ++i) a[i] = *(const float4*)&As[ty * 4 + i][kk];
#pragma unroll
    for (int j = 0; j < 4; ++j) b[j] = *(const float4*)&Bs[tx + 16 * j][kk];
#pragma unroll
    for (int i = 0; i < 4; ++i)
#pragma unroll
      for (int j = 0; j < 4; ++j)
        acc[i][j] += a[i].x * b[j].x + a[i].y * b[j].y +
                     a[i].z * b[j].z + a[i].w * b[j].w;
  }

  // ---- epilogue: scale, write cos, exp, masked row-sum, wave reduce, atomics
#pragma unroll
  for (int i = 0; i < 4; ++i) {
    const int row = by * 64 + ty * 4 + i;
    const int la  = laS[ty * 4 + i];
    const float ina = inaS[ty * 4 + i];
    float esum = 0.0f, nsum = 0.0f;
#pragma unroll
    for (int j = 0; j < 4; ++j) {
      const int cl = tx + 16 * j;                 // col within tile
      float c = acc[i][j] * ina * inbS[cl];
      cos_out[(size_t)row * BATCH + bx * 64 + cl] = c;
      float e = __expf(c * INV_TEMP);
      esum += e;
      nsum += (lbS[cl] == la) ? e : 0.0f;
    }
    // reduce across the 16 tx lanes (low 4 bits of lane id)
#pragma unroll
    for (int m = 1; m < 16; m <<= 1) {
      esum += __shfl_xor(esum, m);
      nsum += __shfl_xor(nsum, m);
    }
    if (tx == 0) {
      atomicAdd(&denom[row], esum);
      atomicAdd(&numer[row], nsum);
    }
  }
}

// ---------------------------------------------------------------------------
// Kernel 3: loss = -mean(log(numer'/denom)), single block
// ---------------------------------------------------------------------------
__global__ __launch_bounds__(256) void loss_kernel(
    const float* __restrict__ numer, const float* __restrict__ denom,
    float* __restrict__ out) {
  __shared__ float red[4];
  float s = 0.0f;
  for (int i = threadIdx.x; i < BATCH; i += 256) {
    float n = numer[i];
    n = (n == 0.0f) ? (n + 0.01f) : n;
    s += logf(n / denom[i]);
  }
#pragma unroll
  for (int m = 32; m; m >>= 1) s += __shfl_xor(s, m);
  if ((threadIdx.x & 63) == 0) red[threadIdx.x >> 6] = s;
  __syncthreads();
  if (threadIdx.x == 0) {
    float t = red[0] + red[1] + red[2] + red[3];
    out[0] = -t / (float)BATCH;
  }
}

// ---------------------------------------------------------------------------
extern "C" void kernel_launch(void* const* d_in, const int* in_sizes, int n_in,
                              void* d_out, int out_size, void* d_ws, size_t ws_size,
                              hipStream_t stream) {
  const int*   labels = (const int*)d_in[0];
  const float* A      = (const float*)d_in[1];
  const float* Bf     = (const float*)d_in[2];
  float* out = (float*)d_out;  // out[0]=loss, out[1..]=cos_score row-major

  float* inv_na = (float*)d_ws;
  float* inv_nb = inv_na + BATCH;
  float* numer  = inv_nb + BATCH;
  float* denom  = numer + BATCH;

  hipLaunchKernelGGL(norm_kernel, dim3(BATCH * 64 / 256), dim3(256), 0, stream,
                     A, Bf, inv_na, inv_nb, numer, denom);
  hipLaunchKernelGGL(cos_tile_kernel, dim3(BATCH / 64, BATCH / 64), dim3(256), 0,
                     stream, A, Bf, labels, inv_na, inv_nb, numer, denom, out + 1);
  hipLaunchKernelGGL(loss_kernel, dim3(1), dim3(256), 0, stream,
                     numer, denom, out);
}

// Round 2
// 415.133 us; speedup vs baseline: 1.1256x; 1.1256x over previous
//
#include <hip/hip_runtime.h>
#include <hip/hip_bf16.h>

#define BATCH 8192
#define DIM 64
#define INV_TEMP 14.2857142857142857f  // 1/0.07
#define EPS_NORM 1e-8f

typedef __attribute__((ext_vector_type(8))) short bf16x8;
typedef __attribute__((ext_vector_type(4))) float f32x4;

__device__ __forceinline__ unsigned short f2bf_rne(float x) {
  unsigned int u = __float_as_uint(x);
  u += 0x7FFFu + ((u >> 16) & 1u);   // round-to-nearest-even
  return (unsigned short)(u >> 16);
}

// ---------------------------------------------------------------------------
// Kernel 1: per-row norms (one wave per row for A and B), write normalized
// bf16 copies; zero numer/denom accumulators (ws is poisoned 0xAA).
// ---------------------------------------------------------------------------
__global__ __launch_bounds__(256) void norm_kernel(
    const float* __restrict__ A, const float* __restrict__ Bm,
    unsigned short* __restrict__ An, unsigned short* __restrict__ Bn,
    float* __restrict__ numer, float* __restrict__ denom) {
  int gid  = blockIdx.x * 256 + threadIdx.x;
  int row  = gid >> 6;
  int lane = gid & 63;
  float a = A[row * DIM + lane];
  float b = Bm[row * DIM + lane];
  float sa = a * a, sb = b * b;
#pragma unroll
  for (int m = 32; m; m >>= 1) {   // butterfly: all lanes end with the sum
    sa += __shfl_xor(sa, m);
    sb += __shfl_xor(sb, m);
  }
  float ia = 1.0f / fmaxf(sqrtf(sa), EPS_NORM);
  float ib = 1.0f / fmaxf(sqrtf(sb), EPS_NORM);
  An[row * DIM + lane] = f2bf_rne(a * ia);
  Bn[row * DIM + lane] = f2bf_rne(b * ib);
  if (lane == 0) {
    numer[row] = 0.0f;
    denom[row] = 0.0f;
  }
}

// ---------------------------------------------------------------------------
// Kernel 2: MFMA cos matrix + fused exp / label-masked row sums.
//   block = 256 threads = 4 waves arranged 2x2 over a 128x128 tile.
//   Each wave: 64x64 region = 4x4 tiles of 16x16, K=64 = 2 MFMA each.
//   A/B fragments loaded straight from global (2 MB total, L2-resident).
//   mfma_f32_16x16x32_bf16: A[m=lane&15][k=(lane>>4)*8+j]; B symmetric;
//   C/D: col=lane&15, row=(lane>>4)*4+reg.
// ---------------------------------------------------------------------------
__global__ __launch_bounds__(256) void cos_mfma_kernel(
    const unsigned short* __restrict__ An, const unsigned short* __restrict__ Bn,
    const int* __restrict__ labels,
    float* __restrict__ numer, float* __restrict__ denom,
    float* __restrict__ cos_out) {
  const int tid  = threadIdx.x;
  const int lane = tid & 63;
  const int wave = tid >> 6;
  const int wr = wave >> 1, wc = wave & 1;
  const int m = lane & 15, q = lane >> 4;
  const int row0 = blockIdx.y * 128 + wr * 64;
  const int col0 = blockIdx.x * 128 + wc * 64;

  // ---- load fragments (dwordx4 each; 16 rows x 64B segments, L2-hit)
  bf16x8 afr[4][2], bfr[4][2];
#pragma unroll
  for (int t = 0; t < 4; ++t) {
    const unsigned short* ap = An + (size_t)(row0 + t * 16 + m) * DIM + q * 8;
    const unsigned short* bp = Bn + (size_t)(col0 + t * 16 + m) * DIM + q * 8;
#pragma unroll
    for (int h = 0; h < 2; ++h) {
      afr[t][h] = *(const bf16x8*)(ap + h * 32);
      bfr[t][h] = *(const bf16x8*)(bp + h * 32);
    }
  }

  // ---- MFMA: 16 tiles x 2 k-steps
  f32x4 acc[4][4];
#pragma unroll
  for (int mt = 0; mt < 4; ++mt)
#pragma unroll
    for (int nt = 0; nt < 4; ++nt) {
      f32x4 a = {0.f, 0.f, 0.f, 0.f};
      a = __builtin_amdgcn_mfma_f32_16x16x32_bf16(afr[mt][0], bfr[nt][0], a, 0, 0, 0);
      a = __builtin_amdgcn_mfma_f32_16x16x32_bf16(afr[mt][1], bfr[nt][1], a, 0, 0, 0);
      acc[mt][nt] = a;
    }

  // ---- labels: own-col label per nt; own-row label per (mt, reg)
  int labc[4];
#pragma unroll
  for (int nt = 0; nt < 4; ++nt) labc[nt] = labels[col0 + nt * 16 + m];
  int lrw[4][4];
#pragma unroll
  for (int mt = 0; mt < 4; ++mt) {
    int lr = labels[row0 + mt * 16 + m];  // lanes 0..15 hold 16 row labels
#pragma unroll
    for (int i = 0; i < 4; ++i) lrw[mt][i] = __shfl(lr, q * 4 + i);
  }

  // ---- epilogue: nontemporal cos store, exp, masked row partials
  float es[4][4], ns[4][4];
#pragma unroll
  for (int mt = 0; mt < 4; ++mt)
#pragma unroll
    for (int i = 0; i < 4; ++i) { es[mt][i] = 0.f; ns[mt][i] = 0.f; }

#pragma unroll
  for (int mt = 0; mt < 4; ++mt) {
#pragma unroll
    for (int nt = 0; nt < 4; ++nt) {
#pragma unroll
      for (int i = 0; i < 4; ++i) {
        float c = acc[mt][nt][i];
        size_t row = (size_t)(row0 + mt * 16 + q * 4 + i);
        __builtin_nontemporal_store(c, cos_out + row * BATCH + col0 + nt * 16 + m);
        float e = __expf(c * INV_TEMP);
        es[mt][i] += e;
        if (labc[nt] == lrw[mt][i]) ns[mt][i] += e;
      }
    }
  }

  // ---- reduce over the 16 col-lanes within each quad (butterfly)
#pragma unroll
  for (int mt = 0; mt < 4; ++mt)
#pragma unroll
    for (int i = 0; i < 4; ++i) {
      float e = es[mt][i], n = ns[mt][i];
#pragma unroll
      for (int msk = 1; msk < 16; msk <<= 1) {
        e += __shfl_xor(e, msk);
        n += __shfl_xor(n, msk);
      }
      es[mt][i] = e; ns[mt][i] = n;
    }

  // ---- combine the two col-half waves through LDS, 1 atomic/row/block
  __shared__ float redN[2][128], redD[2][128];
  if (m == 0) {
#pragma unroll
    for (int mt = 0; mt < 4; ++mt)
#pragma unroll
      for (int i = 0; i < 4; ++i) {
        int r = wr * 64 + mt * 16 + q * 4 + i;
        redN[wc][r] = ns[mt][i];
        redD[wc][r] = es[mt][i];
      }
  }
  __syncthreads();
  if (tid < 128) {
    int row = blockIdx.y * 128 + tid;
    atomicAdd(&numer[row], redN[0][tid] + redN[1][tid]);
    atomicAdd(&denom[row], redD[0][tid] + redD[1][tid]);
  }
}

// ---------------------------------------------------------------------------
// Kernel 3: loss = -mean(log(numer'/denom)), single block
// ---------------------------------------------------------------------------
__global__ __launch_bounds__(256) void loss_kernel(
    const float* __restrict__ numer, const float* __restrict__ denom,
    float* __restrict__ out) {
  __shared__ float red[4];
  float s = 0.0f;
  for (int i = threadIdx.x; i < BATCH; i += 256) {
    float n = numer[i];
    n = (n == 0.0f) ? (n + 0.01f) : n;
    s += logf(n / denom[i]);
  }
#pragma unroll
  for (int m = 32; m; m >>= 1) s += __shfl_xor(s, m);
  if ((threadIdx.x & 63) == 0) red[threadIdx.x >> 6] = s;
  __syncthreads();
  if (threadIdx.x == 0) {
    float t = red[0] + red[1] + red[2] + red[3];
    out[0] = -t / (float)BATCH;
  }
}

// ---------------------------------------------------------------------------
extern "C" void kernel_launch(void* const* d_in, const int* in_sizes, int n_in,
                              void* d_out, int out_size, void* d_ws, size_t ws_size,
                              hipStream_t stream) {
  const int*   labels = (const int*)d_in[0];
  const float* A      = (const float*)d_in[1];
  const float* Bf     = (const float*)d_in[2];
  float* out = (float*)d_out;  // out[0]=loss, out[1..]=cos_score row-major

  unsigned short* An = (unsigned short*)d_ws;                 // 1 MB
  unsigned short* Bn = An + BATCH * DIM;                      // 1 MB
  float* numer = (float*)(Bn + BATCH * DIM);                  // 32 KB
  float* denom = numer + BATCH;                               // 32 KB

  hipLaunchKernelGGL(norm_kernel, dim3(BATCH * 64 / 256), dim3(256), 0, stream,
                     A, Bf, An, Bn, numer, denom);
  hipLaunchKernelGGL(cos_mfma_kernel, dim3(BATCH / 128, BATCH / 128), dim3(256),
                     0, stream, An, Bn, labels, numer, denom, out + 1);
  hipLaunchKernelGGL(loss_kernel, dim3(1), dim3(256), 0, stream,
                     numer, denom, out);
}